// Round 1
// baseline (467.051 us; speedup 1.0000x reference)
//
#include <hip/hip_runtime.h>
#include <math.h>

#define MTOT 9216
#define A_ 36
#define D0_ 64
#define EDGE_ 32
#define RBF_ 16
#define KNN 24
#define QIN_ 67    // D0 + KC
#define KIN_ 99    // D0 + EDGE + KC
#define EPS_ 1e-5f

// ---------------- prep: mask, packed positions, xyz pass-through ----------------
__global__ void k_prep(const int* __restrict__ seq, const float* __restrict__ xyz,
                       const int* __restrict__ aamask,
                       int* __restrict__ mask, float4* __restrict__ pos4,
                       float* __restrict__ out_xyz) {
    int m = blockIdx.x * blockDim.x + threadIdx.x;
    if (m >= MTOT) return;
    int r = m / A_;
    int a = m - r * A_;
    int s = seq[r];
    int mk = (aamask[s * A_ + a] != 0);
    float x0 = xyz[m * 3 + 0], x1 = xyz[m * 3 + 1], x2 = xyz[m * 3 + 2];
    mask[m] = mk;
    pos4[m] = make_float4(x0, x1, x2, mk ? 1.0f : 0.0f);
    out_xyz[m * 3 + 0] = x0;
    out_xyz[m * 3 + 1] = x1;
    out_xyz[m * 3 + 2] = x2;
}

// ---------------- state pass-through copy (masked rows overwritten later) -------
__global__ void k_copy(const float4* __restrict__ src, float4* __restrict__ dst, int n4) {
    int t = blockIdx.x * blockDim.x + threadIdx.x;
    if (t < n4) dst[t] = src[t];
}

// ---------------- exact top-24 neighbor search, histogram select ----------------
#define GA 16
#define CHUNK 2048
#define NBINS 64
#define BINOFF 480
#define CAP 128

__global__ __launch_bounds__(256) void k_nbr(const float4* __restrict__ pos4,
                                             int* __restrict__ idx) {
    __shared__ float4  s_pos[CHUNK];        // 32 KB
    __shared__ unsigned s_hist[GA][NBINS];  // 4 KB
    __shared__ uint2   s_cand[GA][CAP];     // 16 KB
    __shared__ int     s_cnt[GA];
    __shared__ int     s_bstar[GA];

    const int tid = threadIdx.x;
    const int aloc = tid & 15;
    const int part = tid >> 4;
    const int ia = blockIdx.x * GA + aloc;
    const float4 pi = pos4[ia];
    const bool active = pi.w > 0.5f;

    for (int f = tid; f < GA * NBINS; f += 256) ((unsigned*)s_hist)[f] = 0u;
    if (tid < GA) s_cnt[tid] = 0;
    __syncthreads();

    // ---- pass A: per-atom histogram of d2 by float-exponent bin ----
    for (int base = 0; base < MTOT; base += CHUNK) {
        int cn = min(CHUNK, MTOT - base);
        __syncthreads();
        for (int c = tid; c < cn; c += 256) s_pos[c] = pos4[base + c];
        __syncthreads();
        if (active) {
            for (int s = 0; s * 16 + part < cn; ++s) {
                int c = s * 16 + part;
                float4 p = s_pos[c];
                int j = base + c;
                float dx = p.x - pi.x, dy = p.y - pi.y, dz = p.z - pi.z;
                float d2 = dx * dx + dy * dy + dz * dz;
                int bin = min(max((int)(__float_as_uint(d2) >> 21) - BINOFF, 0), NBINS - 1);
                if (p.w > 0.5f && j != ia) atomicAdd(&s_hist[aloc][bin], 1u);
            }
        }
    }
    __syncthreads();

    // ---- find bin containing the 24th smallest ----
    if (tid < GA) {
        int cum = 0, bs = NBINS - 1;
        for (int b = 0; b < NBINS; ++b) {
            cum += (int)s_hist[tid][b];
            if (cum >= KNN) { bs = b; break; }
        }
        s_bstar[tid] = bs;
    }
    __syncthreads();
    const int bstar = s_bstar[aloc];

    // ---- pass B: collect candidates at-or-below threshold bin ----
    for (int base = 0; base < MTOT; base += CHUNK) {
        int cn = min(CHUNK, MTOT - base);
        __syncthreads();
        for (int c = tid; c < cn; c += 256) s_pos[c] = pos4[base + c];
        __syncthreads();
        if (active) {
            for (int s = 0; s * 16 + part < cn; ++s) {
                int c = s * 16 + part;
                float4 p = s_pos[c];
                int j = base + c;
                float dx = p.x - pi.x, dy = p.y - pi.y, dz = p.z - pi.z;
                float d2 = dx * dx + dy * dy + dz * dz;
                unsigned bits = __float_as_uint(d2);
                int bin = min(max((int)(bits >> 21) - BINOFF, 0), NBINS - 1);
                if (p.w > 0.5f && j != ia && bin <= bstar) {
                    int pos = atomicAdd(&s_cnt[aloc], 1);
                    if (pos < CAP) s_cand[aloc][pos] = make_uint2(bits, (unsigned)j);
                }
            }
        }
    }
    __syncthreads();

    // ---- exact rank select among collected (lex order (d2, j) == lax.top_k) ----
    for (int f = tid; f < GA * CAP; f += 256) {
        int a = f >> 7;            // CAP = 128
        int c = f & (CAP - 1);
        int n = min(s_cnt[a], CAP);
        if (c < n) {
            uint2 my = s_cand[a][c];
            int rank = 0;
            for (int c2 = 0; c2 < n; ++c2) {
                uint2 o = s_cand[a][c2];
                rank += (o.x < my.x) || (o.x == my.x && o.y < my.y);
            }
            if (rank < KNN) idx[(blockIdx.x * GA + a) * KNN + rank] = (int)my.y;
        }
    }
}

// ---------------- per-atom equivariant attention (1 wave / atom) ----------------
__global__ __launch_bounds__(64) void k_attn(
    const float* __restrict__ xyz, const int* __restrict__ seq,
    const int* __restrict__ num_bonds, const float* __restrict__ state,
    const float* __restrict__ grads,
    const float* __restrict__ We, const float* __restrict__ be,
    const float* __restrict__ Wq, const float* __restrict__ Wk,
    const float* __restrict__ Wv0, const float* __restrict__ Wv1,
    const float* __restrict__ Wo0, const float* __restrict__ Wself,
    const float* __restrict__ b0,
    const int* __restrict__ mask, const int* __restrict__ idxbuf,
    float* __restrict__ out_xyz, float* __restrict__ out_state) {
    const int i = blockIdx.x;
    if (!mask[i]) return;
    const int lane = threadIdx.x;
    const int l15 = lane & 15;
    const int h = lane >> 4;

    __shared__ float s_kin[KNN][100];   // [node0(64) | e(32) | inv(3) | pad]
    __shared__ float s_dir[KNN][4];     // dirv xyz + dist
    __shared__ float s_rbf[KNN][RBF_];
    __shared__ float s_l1j[KNN][3][3];
    __shared__ float s_qin[QIN_ + 1];
    __shared__ float s_o0[64];
    __shared__ float s_attn[4][KNN];
    __shared__ float s_v1[KNN][16];
    __shared__ float s_coef[KNN][4];
    __shared__ int   s_j[KNN];
    __shared__ int   s_ok[KNN];
    __shared__ int   s_bc[KNN];
    __shared__ float s_xi[3];

    // ---- stage per-atom inputs ----
    s_qin[lane] = state[i * D0_ + lane];
    if (lane < 3) {
        float g0 = grads[(lane * MTOT + i) * 3 + 0];
        float g1 = grads[(lane * MTOT + i) * 3 + 1];
        float g2 = grads[(lane * MTOT + i) * 3 + 2];
        s_qin[D0_ + lane] = sqrtf(g0 * g0 + g1 * g1 + g2 * g2 + EPS_);
        s_xi[lane] = xyz[i * 3 + lane];
    }
    if (lane < KNN) {
        int j = idxbuf[i * KNN + lane];
        int ok = (j >= 0 && j < MTOT);
        int jj = ok ? j : 0;
        s_j[lane] = jj;
        s_ok[lane] = ok;
        float dx = xyz[jj * 3 + 0] - xyz[i * 3 + 0];
        float dy = xyz[jj * 3 + 1] - xyz[i * 3 + 1];
        float dz = xyz[jj * 3 + 2] - xyz[i * 3 + 2];
        float dist = sqrtf(dx * dx + dy * dy + dz * dz + EPS_);
        s_dir[lane][0] = dx / dist;
        s_dir[lane][1] = dy / dist;
        s_dir[lane][2] = dz / dist;
        s_dir[lane][3] = dist;
        int ri = i / A_, ai = i - ri * A_;
        int rj = jj / A_, aj = jj - rj * A_;
        int b = 0;
        if (rj == ri) b = num_bonds[(seq[ri] * A_ + ai) * A_ + aj];
        s_bc[lane] = min(max(b, 0), 4);
    }
    __syncthreads();

    // ---- q projection (lane owns one of 64 outputs) ----
    float qreg = 0.0f;
    for (int c = 0; c < QIN_; ++c) qreg += s_qin[c] * Wq[c * 64 + lane];

    // ---- rbf(dist) for all 24 neighbors ----
    for (int f = lane; f < KNN * RBF_; f += 64) {
        int k = f >> 4, r = f & 15;
        float mu = (6.0f / 15.0f) * (float)r;
        float d = s_dir[k][3] - mu;
        s_rbf[k][r] = expf(-d * d * 2.0f);   // 2*sigma^2 = 0.5
    }
    // ---- gather neighbor node0 into kin[:, 0:64] ----
    for (int k = 0; k < KNN; ++k) s_kin[k][lane] = state[s_j[k] * D0_ + lane];
    // ---- l1 invariants: kin[:, 96:99], stash l1j for vector message ----
    for (int f = lane; f < KNN * 3; f += 64) {
        int k = f / 3, c = f - 3 * k;
        int jj = s_j[k];
        float g0 = grads[(c * MTOT + jj) * 3 + 0];
        float g1 = grads[(c * MTOT + jj) * 3 + 1];
        float g2 = grads[(c * MTOT + jj) * 3 + 2];
        s_l1j[k][c][0] = g0; s_l1j[k][c][1] = g1; s_l1j[k][c][2] = g2;
        s_kin[k][96 + c] = g0 * s_dir[k][0] + g1 * s_dir[k][1] + g2 * s_dir[k][2];
    }
    if (lane < KNN) s_kin[lane][99] = 0.0f;
    __syncthreads();

    // ---- edge embedding e = [rbf | onehot(bond)] @ We + be -> kin[:, 64:96] ----
    for (int f = lane; f < KNN * EDGE_; f += 64) {
        int k = f >> 5, d2i = f & 31;
        float acc = be[d2i] + We[(RBF_ + s_bc[k]) * EDGE_ + d2i];
        #pragma unroll
        for (int r = 0; r < RBF_; ++r) acc += s_rbf[k][r] * We[r * EDGE_ + d2i];
        s_kin[k][64 + d2i] = acc;
    }
    __syncthreads();

    // ---- K / V0 / V1 projections: lane owns output dim, 24 neighbor accumulators ----
    float ak[KNN], av0[KNN], av1[KNN];
    #pragma unroll
    for (int k = 0; k < KNN; ++k) { ak[k] = 0.0f; av0[k] = 0.0f; av1[k] = 0.0f; }

    for (int cb = 0; cb < 96; cb += 4) {
        float wk0 = Wk[(cb + 0) * 64 + lane], wk1 = Wk[(cb + 1) * 64 + lane];
        float wk2 = Wk[(cb + 2) * 64 + lane], wk3 = Wk[(cb + 3) * 64 + lane];
        float w00 = Wv0[(cb + 0) * 64 + lane], w01 = Wv0[(cb + 1) * 64 + lane];
        float w02 = Wv0[(cb + 2) * 64 + lane], w03 = Wv0[(cb + 3) * 64 + lane];
        float w10 = Wv1[(cb + 0) * 16 + l15], w11 = Wv1[(cb + 1) * 16 + l15];
        float w12 = Wv1[(cb + 2) * 16 + l15], w13 = Wv1[(cb + 3) * 16 + l15];
        #pragma unroll
        for (int k = 0; k < KNN; ++k) {
            const float4 t = *(const float4*)&s_kin[k][cb];
            ak[k]  += t.x * wk0 + t.y * wk1 + t.z * wk2 + t.w * wk3;
            av0[k] += t.x * w00 + t.y * w01 + t.z * w02 + t.w * w03;
            av1[k] += t.x * w10 + t.y * w11 + t.z * w12 + t.w * w13;
        }
    }
    for (int c = 96; c < 99; ++c) {
        float wk = Wk[c * 64 + lane];
        float w0 = Wv0[c * 64 + lane];
        float w1 = Wv1[c * 16 + l15];
        #pragma unroll
        for (int k = 0; k < KNN; ++k) {
            float t = s_kin[k][c];
            ak[k] += t * wk; av0[k] += t * w0; av1[k] += t * w1;
        }
    }

    // ---- logits: 16-lane reduce of q.k within each head group ----
    float logit[KNN];
    #pragma unroll
    for (int k = 0; k < KNN; ++k) {
        float t = qreg * ak[k];
        t += __shfl_xor(t, 8, 64);
        t += __shfl_xor(t, 4, 64);
        t += __shfl_xor(t, 2, 64);
        t += __shfl_xor(t, 1, 64);
        logit[k] = s_ok[k] ? t * 0.25f : -1e9f;
    }
    // ---- softmax over 24 neighbors (per lane; identical within head group) ----
    float mx = -1e30f;
    #pragma unroll
    for (int k = 0; k < KNN; ++k) mx = fmaxf(mx, logit[k]);
    float attn[KNN];
    float ssum = 0.0f;
    #pragma unroll
    for (int k = 0; k < KNN; ++k) { attn[k] = expf(logit[k] - mx); ssum += attn[k]; }
    float rs = 1.0f / ssum;
    #pragma unroll
    for (int k = 0; k < KNN; ++k) attn[k] *= rs;

    // ---- o0 + stash attn / v1 for coef phase ----
    float o0 = 0.0f;
    #pragma unroll
    for (int k = 0; k < KNN; ++k) o0 += attn[k] * av0[k];
    s_o0[lane] = o0;
    #pragma unroll
    for (int k = 0; k < KNN; ++k) if ((k >> 1) == l15) s_attn[h][k] = attn[k];
    #pragma unroll
    for (int k = 0; k < KNN; ++k) if ((k / 6) == h) s_v1[k][l15] = av1[k];
    __syncthreads();

    // ---- out0 = o0 @ Wo0 + node0 @ Wself + b0 ----
    float acc = b0[lane];
    for (int t = 0; t < 64; ++t) acc += s_o0[t] * Wo0[t * 64 + lane];
    for (int t = 0; t < 64; ++t) acc += s_qin[t] * Wself[t * 64 + lane];
    out_state[i * D0_ + lane] = acc;

    // ---- coef[k][c] = sum_h attn[h][k] * v1[k][h][c] ----
    for (int f = lane; f < KNN * 4; f += 64) {
        int k = f >> 2, c = f & 3;
        float a2 = 0.0f;
        #pragma unroll
        for (int hh = 0; hh < 4; ++hh) a2 += s_attn[hh][k] * s_v1[k][hh * 4 + c];
        s_coef[k][c] = a2;
    }
    __syncthreads();

    // ---- vector message sum -> xyz shift ----
    if (lane < 3) {
        float o1 = 0.0f;
        #pragma unroll
        for (int k = 0; k < KNN; ++k) {
            float t = s_coef[k][0] * s_dir[k][lane];
            t += s_coef[k][1] * s_l1j[k][0][lane];
            t += s_coef[k][2] * s_l1j[k][1][lane];
            t += s_coef[k][3] * s_l1j[k][2][lane];
            o1 += t;
        }
        out_xyz[i * 3 + lane] = s_xi[lane] + o1 / 100.0f;
    }
}

extern "C" void kernel_launch(void* const* d_in, const int* in_sizes, int n_in,
                              void* d_out, int out_size, void* d_ws, size_t ws_size,
                              hipStream_t stream) {
    const int*   seq    = (const int*)d_in[0];
    const float* xyz    = (const float*)d_in[1];
    const int*   aamask = (const int*)d_in[2];   // bool canonicalized to int32
    const int*   nbonds = (const int*)d_in[3];
    const float* state  = (const float*)d_in[4];
    const float* grads  = (const float*)d_in[5];
    // d_in[6] = top_k (24, compile-time KNN)
    const float* We    = (const float*)d_in[7];
    const float* be    = (const float*)d_in[8];
    const float* Wq    = (const float*)d_in[9];
    const float* Wk    = (const float*)d_in[10];
    const float* Wv0   = (const float*)d_in[11];
    const float* Wv1   = (const float*)d_in[12];
    const float* Wo0   = (const float*)d_in[13];
    const float* Wself = (const float*)d_in[14];
    const float* b0    = (const float*)d_in[15];

    float* out_xyz   = (float*)d_out;
    float* out_state = out_xyz + MTOT * 3;

    char* ws = (char*)d_ws;
    int*    mask = (int*)ws;                          // 36864 B
    float4* pos4 = (float4*)(ws + 36864);             // 147456 B
    int*    idx  = (int*)(ws + 36864 + 147456);       // 884736 B

    k_prep<<<(MTOT + 255) / 256, 256, 0, stream>>>(seq, xyz, aamask, mask, pos4, out_xyz);
    k_copy<<<(MTOT * D0_ / 4 + 255) / 256, 256, 0, stream>>>(
        (const float4*)state, (float4*)out_state, MTOT * D0_ / 4);
    k_nbr<<<MTOT / GA, 256, 0, stream>>>(pos4, idx);
    k_attn<<<MTOT, 64, 0, stream>>>(xyz, seq, nbonds, state, grads, We, be, Wq, Wk,
                                    Wv0, Wv1, Wo0, Wself, b0, mask, idx,
                                    out_xyz, out_state);
}

// Round 2
// 329.593 us; speedup vs baseline: 1.4171x; 1.4171x over previous
//
#include <hip/hip_runtime.h>
#include <math.h>

#define MTOT 9216
#define A_ 36
#define D0_ 64
#define EDGE_ 32
#define RBF_ 16
#define KNN 24
#define QIN_ 67    // D0 + KC
#define EPS_ 1e-5f

// ---------------- zero the active-atom counter ----------------
__global__ void k_zero(int* cnt) { if (threadIdx.x == 0) *cnt = 0; }

// ---------------- prep: mask, packed positions, xyz pass-through, active list --
__global__ void k_prep(const int* __restrict__ seq, const float* __restrict__ xyz,
                       const int* __restrict__ aamask,
                       int* __restrict__ mask, float4* __restrict__ pos4,
                       float* __restrict__ out_xyz,
                       int* __restrict__ list, int* __restrict__ cnt) {
    int m = blockIdx.x * blockDim.x + threadIdx.x;
    if (m >= MTOT) return;
    int r = m / A_;
    int a = m - r * A_;
    int mk = (aamask[seq[r] * A_ + a] != 0);
    float x0 = xyz[m * 3 + 0], x1 = xyz[m * 3 + 1], x2 = xyz[m * 3 + 2];
    mask[m] = mk;
    pos4[m] = make_float4(x0, x1, x2, mk ? 1.0f : 0.0f);
    out_xyz[m * 3 + 0] = x0;
    out_xyz[m * 3 + 1] = x1;
    out_xyz[m * 3 + 2] = x2;
    if (mk) { int p = atomicAdd(cnt, 1); list[p] = m; }
}

// ---------------- state pass-through copy ----------------
__global__ void k_copy(const float4* __restrict__ src, float4* __restrict__ dst, int n4) {
    int t = blockIdx.x * blockDim.x + threadIdx.x;
    if (t < n4) dst[t] = src[t];
}

// ---------------- exact top-24 via private-histogram select ----------------
#define GA 16
#define CHUNK 512
#define NB 32
#define HSTR 33     // u32 stride: bank = (tid + bin) % 32, conflict-free-ish
#define BOFF 240    // bin = (bits(d2)>>22) - 240, clamped [0,31]
#define CAP 128

__global__ __launch_bounds__(256, 2) void k_nbr(const float4* __restrict__ pos4,
                                                const int* __restrict__ list,
                                                const int* __restrict__ cnt,
                                                int* __restrict__ idx) {
    __shared__ float4   s_pos[CHUNK];          // 8 KB
    __shared__ unsigned s_hist[256 * HSTR];    // 33.8 KB
    __shared__ uint2    s_cand[GA][CAP];       // 16 KB
    __shared__ int      s_cnt[GA];
    __shared__ int      s_bstar[GA];
    __shared__ int      s_ia[GA];

    const int n_act = *cnt;
    if ((int)(blockIdx.x * GA) >= n_act) return;     // uniform exit

    const int tid = threadIdx.x;
    const int aloc = tid & 15;
    const int part = tid >> 4;
    const int slot = blockIdx.x * GA + aloc;
    const bool active = slot < n_act;
    int ia = 0;
    float4 pi = make_float4(0.f, 0.f, 0.f, 0.f);
    if (active) { ia = list[slot]; pi = pos4[ia]; }
    if (tid < GA) {
        s_cnt[tid] = 0;
        s_ia[tid] = (blockIdx.x * GA + tid < n_act) ? list[blockIdx.x * GA + tid] : -1;
    }
    for (int f = tid; f < 256 * HSTR; f += 256) s_hist[f] = 0u;
    __syncthreads();

    unsigned* myh = &s_hist[tid * HSTR];

    // ---- pass A: private per-thread histogram (ds_add, zero contention) ----
    for (int base = 0; base < MTOT; base += CHUNK) {
        for (int c = tid; c < CHUNK; c += 256) s_pos[c] = pos4[base + c];
        __syncthreads();
        if (active) {
            for (int c = part; c < CHUNK; c += 16) {
                float4 p = s_pos[c];
                int j = base + c;
                float dx = p.x - pi.x, dy = p.y - pi.y, dz = p.z - pi.z;
                float d2 = dx * dx + dy * dy + dz * dz;
                int bin = min(max((int)(__float_as_uint(d2) >> 22) - BOFF, 0), NB - 1);
                if (p.w > 0.5f && j != ia) atomicAdd(&myh[bin], 1u);
            }
        }
        __syncthreads();
    }

    // ---- reduce 16 partitions, find bin of 24th smallest ----
    if (tid < GA) {
        int cum = 0, bs = NB - 1;
        for (int b = 0; b < NB; ++b) {
            int s = 0;
            #pragma unroll
            for (int p = 0; p < 16; ++p) s += (int)s_hist[(p * 16 + tid) * HSTR + b];
            cum += s;
            if (cum >= KNN) { bs = b; break; }
        }
        s_bstar[tid] = bs;
    }
    __syncthreads();
    const int bstar = s_bstar[aloc];

    // ---- pass B: collect candidates at-or-below threshold bin ----
    for (int base = 0; base < MTOT; base += CHUNK) {
        for (int c = tid; c < CHUNK; c += 256) s_pos[c] = pos4[base + c];
        __syncthreads();
        if (active) {
            for (int c = part; c < CHUNK; c += 16) {
                float4 p = s_pos[c];
                int j = base + c;
                float dx = p.x - pi.x, dy = p.y - pi.y, dz = p.z - pi.z;
                float d2 = dx * dx + dy * dy + dz * dz;
                unsigned bits = __float_as_uint(d2);
                int bin = min(max((int)(bits >> 22) - BOFF, 0), NB - 1);
                if (p.w > 0.5f && j != ia && bin <= bstar) {
                    int pos = atomicAdd(&s_cnt[aloc], 1);
                    if (pos < CAP) s_cand[aloc][pos] = make_uint2(bits, (unsigned)j);
                }
            }
        }
        __syncthreads();
    }

    // ---- exact rank select among collected ((d2,j) lex == lax.top_k) ----
    for (int f = tid; f < GA * CAP; f += 256) {
        int a = f >> 7;
        int c = f & (CAP - 1);
        int n = min(s_cnt[a], CAP);
        if (s_ia[a] >= 0 && c < n) {
            uint2 my = s_cand[a][c];
            int rank = 0;
            for (int c2 = 0; c2 < n; ++c2) {
                uint2 o = s_cand[a][c2];
                rank += (o.x < my.x) || (o.x == my.x && o.y < my.y);
            }
            if (rank < KNN) idx[s_ia[a] * KNN + rank] = (int)my.y;
        }
    }
}

// ---------------- per-atom attention, rank-reduced (1 wave / active atom) -------
__global__ __launch_bounds__(64, 2) void k_attn(
    const float* __restrict__ xyz, const int* __restrict__ seq,
    const int* __restrict__ num_bonds, const float* __restrict__ state,
    const float* __restrict__ grads,
    const float* __restrict__ We, const float* __restrict__ be,
    const float* __restrict__ Wq, const float* __restrict__ Wk,
    const float* __restrict__ Wv0, const float* __restrict__ Wv1,
    const float* __restrict__ Wo0, const float* __restrict__ Wself,
    const float* __restrict__ b0,
    const int* __restrict__ list, const int* __restrict__ cnt,
    const int* __restrict__ idxbuf,
    float* __restrict__ out_xyz, float* __restrict__ out_state) {
    const int nact = *cnt;
    if ((int)blockIdx.x >= nact) return;
    const int i = list[blockIdx.x];
    const int lane = threadIdx.x;
    const int l15 = lane & 15;
    const int h = lane >> 4;

    __shared__ float s_kin[KNN][100];   // [node0(64) | e(32) | inv(3) | pad]
    __shared__ float s_qw[4][100];      // Wk folded with q, per head
    __shared__ float s_wkin[4][100];    // attn-weighted kin, per head
    __shared__ float s_dir[KNN][4];
    __shared__ float s_rbf[KNN][RBF_];
    __shared__ float s_l1j[KNN][3][3];
    __shared__ float s_qin[68];
    __shared__ float s_q[64];
    __shared__ float s_logit[4][KNN];
    __shared__ float s_attn[4][KNN];
    __shared__ float s_o0[64];
    __shared__ float s_v1[KNN][16];
    __shared__ float s_coef[KNN][4];
    __shared__ int   s_j[KNN];
    __shared__ int   s_ok[KNN];
    __shared__ int   s_bc[KNN];
    __shared__ float s_xi[3];

    // ---- stage per-atom inputs ----
    s_qin[lane] = state[i * D0_ + lane];
    if (lane < 3) {
        float g0 = grads[(lane * MTOT + i) * 3 + 0];
        float g1 = grads[(lane * MTOT + i) * 3 + 1];
        float g2 = grads[(lane * MTOT + i) * 3 + 2];
        s_qin[D0_ + lane] = sqrtf(g0 * g0 + g1 * g1 + g2 * g2 + EPS_);
        s_xi[lane] = xyz[i * 3 + lane];
    }
    if (lane < KNN) {
        int j = idxbuf[i * KNN + lane];
        int ok = (j >= 0 && j < MTOT);
        int jj = ok ? j : 0;
        s_j[lane] = jj;
        s_ok[lane] = ok;
        float dx = xyz[jj * 3 + 0] - xyz[i * 3 + 0];
        float dy = xyz[jj * 3 + 1] - xyz[i * 3 + 1];
        float dz = xyz[jj * 3 + 2] - xyz[i * 3 + 2];
        float dist = sqrtf(dx * dx + dy * dy + dz * dz + EPS_);
        s_dir[lane][0] = dx / dist;
        s_dir[lane][1] = dy / dist;
        s_dir[lane][2] = dz / dist;
        s_dir[lane][3] = dist;
        int ri = i / A_, ai = i - ri * A_;
        int rj = jj / A_, aj = jj - rj * A_;
        int b = 0;
        if (rj == ri) b = num_bonds[(seq[ri] * A_ + ai) * A_ + aj];
        s_bc[lane] = min(max(b, 0), 4);
    }
    __syncthreads();

    // ---- q projection; stash for the qW fold ----
    {
        float q = 0.0f;
        for (int c = 0; c < QIN_; ++c) q += s_qin[c] * Wq[c * 64 + lane];
        s_q[lane] = q;
    }
    // ---- rbf ----
    for (int f = lane; f < KNN * RBF_; f += 64) {
        int k = f >> 4, r = f & 15;
        float mu = (6.0f / 15.0f) * (float)r;
        float d = s_dir[k][3] - mu;
        s_rbf[k][r] = expf(-d * d * 2.0f);
    }
    // ---- neighbor node0 gather ----
    for (int k = 0; k < KNN; ++k) s_kin[k][lane] = state[s_j[k] * D0_ + lane];
    // ---- l1 invariants + stash l1j ----
    for (int f = lane; f < KNN * 3; f += 64) {
        int k = f / 3, c = f - 3 * k;
        int jj = s_j[k];
        float g0 = grads[(c * MTOT + jj) * 3 + 0];
        float g1 = grads[(c * MTOT + jj) * 3 + 1];
        float g2 = grads[(c * MTOT + jj) * 3 + 2];
        s_l1j[k][c][0] = g0; s_l1j[k][c][1] = g1; s_l1j[k][c][2] = g2;
        s_kin[k][96 + c] = g0 * s_dir[k][0] + g1 * s_dir[k][1] + g2 * s_dir[k][2];
    }
    if (lane < KNN) s_kin[lane][99] = 0.0f;
    __syncthreads();

    // ---- edge embedding -> kin[:, 64:96] ----
    for (int f = lane; f < KNN * EDGE_; f += 64) {
        int k = f >> 5, d = f & 31;
        float acc = be[d] + We[(RBF_ + s_bc[k]) * EDGE_ + d];
        #pragma unroll
        for (int r = 0; r < RBF_; ++r) acc += s_rbf[k][r] * We[r * EDGE_ + d];
        s_kin[k][64 + d] = acc;
    }
    // ---- fold q into Wk: qW[h][c] = sum_d q[h,d] * Wk[c, h*16+d] ----
    for (int t = 0; t < 7; ++t) {
        int c = t * 16 + l15;
        if (c < 99) {
            const float* wk = &Wk[c * 64 + h * 16];
            float acc = 0.0f;
            #pragma unroll
            for (int d = 0; d < 16; ++d) acc += s_q[h * 16 + d] * wk[d];
            s_qw[h][c] = acc;
        }
    }
    __syncthreads();

    // ---- logits[h][k] = kin[k] . qW[h] (96 dots of length 99) ----
    for (int f = lane; f < 96; f += 64) {
        int k = f >> 2, hh = f & 3;
        const float4* k4 = (const float4*)s_kin[k];
        const float4* q4 = (const float4*)s_qw[hh];
        float acc = 0.0f;
        #pragma unroll
        for (int c4 = 0; c4 < 24; ++c4) {
            float4 a = k4[c4], b = q4[c4];
            acc += a.x * b.x + a.y * b.y + a.z * b.z + a.w * b.w;
        }
        acc += s_kin[k][96] * s_qw[hh][96] + s_kin[k][97] * s_qw[hh][97]
             + s_kin[k][98] * s_qw[hh][98];
        s_logit[hh][k] = s_ok[k] ? acc * 0.25f : -1e9f;
    }
    __syncthreads();

    // ---- softmax (each lane redundantly for its head; attn stays in regs) ----
    float attn[KNN];
    {
        float mx = -1e30f;
        #pragma unroll
        for (int k = 0; k < KNN; ++k) { attn[k] = s_logit[h][k]; mx = fmaxf(mx, attn[k]); }
        float ss = 0.0f;
        #pragma unroll
        for (int k = 0; k < KNN; ++k) { attn[k] = expf(attn[k] - mx); ss += attn[k]; }
        float rs = 1.0f / ss;
        #pragma unroll
        for (int k = 0; k < KNN; ++k) attn[k] *= rs;
    }
    s_attn[h][l15] = attn[l15];
    if (l15 < 8) s_attn[h][16 + l15] = attn[16 + l15];

    // ---- wkin[h][c] = sum_k attn[k] * kin[k][c] ----
    for (int t = 0; t < 7; ++t) {
        int c = t * 16 + l15;
        if (c < 99) {
            float acc = 0.0f;
            #pragma unroll
            for (int k = 0; k < KNN; ++k) acc += attn[k] * s_kin[k][c];
            s_wkin[h][c] = acc;
        }
    }
    // ---- v1[k][u] = kin[k] . Wv1[:,u]  (384 dots of length 99) ----
    for (int t = 0; t < 6; ++t) {
        int k = (t * 64 + lane) >> 4;
        const float4* k4 = (const float4*)s_kin[k];
        const float* wv = &Wv1[l15];
        float acc = 0.0f;
        #pragma unroll
        for (int c4 = 0; c4 < 24; ++c4) {
            float4 a = k4[c4];
            acc += a.x * wv[(c4 * 4 + 0) * 16] + a.y * wv[(c4 * 4 + 1) * 16]
                 + a.z * wv[(c4 * 4 + 2) * 16] + a.w * wv[(c4 * 4 + 3) * 16];
        }
        acc += s_kin[k][96] * wv[96 * 16] + s_kin[k][97] * wv[97 * 16]
             + s_kin[k][98] * wv[98 * 16];
        s_v1[k][l15] = acc;
    }
    __syncthreads();

    // ---- o0[lane] = sum_c wkin[h][c] * Wv0[c, lane] ----
    {
        float o0 = 0.0f;
        for (int c = 0; c < 99; ++c) o0 += s_wkin[h][c] * Wv0[c * 64 + lane];
        s_o0[lane] = o0;
    }
    __syncthreads();

    // ---- out0 = o0 @ Wo0 + node0 @ Wself + b0 ----
    {
        float acc = b0[lane];
        for (int t = 0; t < 64; ++t) acc += s_o0[t] * Wo0[t * 64 + lane];
        for (int t = 0; t < 64; ++t) acc += s_qin[t] * Wself[t * 64 + lane];
        out_state[i * D0_ + lane] = acc;
    }
    // ---- coef[k][c] = sum_h attn[h][k] * v1[k][h*4+c] ----
    for (int f = lane; f < KNN * 4; f += 64) {
        int k = f >> 2, c = f & 3;
        float a2 = 0.0f;
        #pragma unroll
        for (int hh = 0; hh < 4; ++hh) a2 += s_attn[hh][k] * s_v1[k][hh * 4 + c];
        s_coef[k][c] = a2;
    }
    __syncthreads();

    // ---- vector message -> xyz shift ----
    if (lane < 3) {
        float o1 = 0.0f;
        #pragma unroll
        for (int k = 0; k < KNN; ++k) {
            float t = s_coef[k][0] * s_dir[k][lane];
            t += s_coef[k][1] * s_l1j[k][0][lane];
            t += s_coef[k][2] * s_l1j[k][1][lane];
            t += s_coef[k][3] * s_l1j[k][2][lane];
            o1 += t;
        }
        out_xyz[i * 3 + lane] = s_xi[lane] + o1 / 100.0f;
    }
}

extern "C" void kernel_launch(void* const* d_in, const int* in_sizes, int n_in,
                              void* d_out, int out_size, void* d_ws, size_t ws_size,
                              hipStream_t stream) {
    const int*   seq    = (const int*)d_in[0];
    const float* xyz    = (const float*)d_in[1];
    const int*   aamask = (const int*)d_in[2];
    const int*   nbonds = (const int*)d_in[3];
    const float* state  = (const float*)d_in[4];
    const float* grads  = (const float*)d_in[5];
    const float* We    = (const float*)d_in[7];
    const float* be    = (const float*)d_in[8];
    const float* Wq    = (const float*)d_in[9];
    const float* Wk    = (const float*)d_in[10];
    const float* Wv0   = (const float*)d_in[11];
    const float* Wv1   = (const float*)d_in[12];
    const float* Wo0   = (const float*)d_in[13];
    const float* Wself = (const float*)d_in[14];
    const float* b0    = (const float*)d_in[15];

    float* out_xyz   = (float*)d_out;
    float* out_state = out_xyz + MTOT * 3;

    char* ws = (char*)d_ws;
    int*    cnt  = (int*)ws;                            // 16 B
    int*    mask = (int*)(ws + 16);                     // 36864 B
    float4* pos4 = (float4*)(ws + 16 + 36864);          // 147456 B (16B aligned)
    int*    idx  = (int*)(ws + 16 + 36864 + 147456);    // 884736 B
    int*    list = (int*)(ws + 16 + 36864 + 147456 + 884736);  // 36864 B

    k_zero<<<1, 64, 0, stream>>>(cnt);
    k_prep<<<(MTOT + 255) / 256, 256, 0, stream>>>(seq, xyz, aamask, mask, pos4,
                                                   out_xyz, list, cnt);
    k_copy<<<(MTOT * D0_ / 4 + 255) / 256, 256, 0, stream>>>(
        (const float4*)state, (float4*)out_state, MTOT * D0_ / 4);
    k_nbr<<<MTOT / GA, 256, 0, stream>>>(pos4, list, cnt, idx);
    k_attn<<<MTOT, 64, 0, stream>>>(xyz, seq, nbonds, state, grads, We, be, Wq, Wk,
                                    Wv0, Wv1, Wo0, Wself, b0, list, cnt, idx,
                                    out_xyz, out_state);
}

// Round 3
// 228.708 us; speedup vs baseline: 2.0421x; 1.4411x over previous
//
#include <hip/hip_runtime.h>
#include <math.h>

#define MTOT 9216
#define A_ 36
#define D0_ 64
#define EDGE_ 32
#define RBF_ 16
#define KNN 24
#define QIN_ 67    // D0 + KC
#define EPS_ 1e-5f

// ---------------- zero the active-atom counter ----------------
__global__ void k_zero(int* cnt) { if (threadIdx.x == 0) *cnt = 0; }

// ------- prep: xyz pass-through + packed active list (pos + index in .w) -------
__global__ void k_prep(const int* __restrict__ seq, const float* __restrict__ xyz,
                       const int* __restrict__ aamask,
                       float4* __restrict__ pact, float* __restrict__ out_xyz,
                       int* __restrict__ cnt) {
    int m = blockIdx.x * blockDim.x + threadIdx.x;
    if (m >= MTOT) return;
    int r = m / A_;
    int a = m - r * A_;
    int mk = (aamask[seq[r] * A_ + a] != 0);
    float x0 = xyz[m * 3 + 0], x1 = xyz[m * 3 + 1], x2 = xyz[m * 3 + 2];
    out_xyz[m * 3 + 0] = x0;
    out_xyz[m * 3 + 1] = x1;
    out_xyz[m * 3 + 2] = x2;
    if (mk) {
        int p = atomicAdd(cnt, 1);
        pact[p] = make_float4(x0, x1, x2, __int_as_float(m));
    }
}

// ---------------- state pass-through copy ----------------
__global__ void k_copy(const float4* __restrict__ src, float4* __restrict__ dst, int n4) {
    int t = blockIdx.x * blockDim.x + threadIdx.x;
    if (t < n4) dst[t] = src[t];
}

// ------- exact top-24, wave-per-atom, ballot histogram (no LDS atomics) --------
#define CAP 128
#define WPB 4    // waves per block

__global__ __launch_bounds__(256) void k_nbr(const float4* __restrict__ pact,
                                             const int* __restrict__ cnt,
                                             int* __restrict__ idx) {
    __shared__ uint2 s_cand[WPB][CAP];   // per-wave slice, 4 KB total

    const int nact = *cnt;
    const int lane = threadIdx.x & 63;
    const int wv = threadIdx.x >> 6;
    const int slot = blockIdx.x * WPB + wv;
    if (slot >= nact) return;            // wave-uniform exit; no barriers anywhere

    const float4 pq = pact[slot];
    const int ia = __float_as_int(pq.w);
    const unsigned long long lmask = (1ULL << lane) - 1ULL;

    // ---- pass A: cumulative exponent-bin histogram via ballots ----
    unsigned cum[32];
    #pragma unroll
    for (int b = 0; b < 32; ++b) cum[b] = 0u;

    for (int base = 0; base < nact; base += 64) {
        int c = base + lane;                      // pact padded: OOB-safe read
        float4 p = pact[c];
        int j = __float_as_int(p.w);
        float dx = p.x - pq.x, dy = p.y - pq.y, dz = p.z - pq.z;
        float d2 = dx * dx + dy * dy + dz * dz;
        unsigned bits = __float_as_uint(d2);
        int bb = min(max((int)(bits >> 22) - 240, 0), 31);
        unsigned bin = (c < nact && j != ia) ? (unsigned)bb : 1000u;
        #pragma unroll
        for (int b = 0; b < 32; ++b)
            cum[b] += (unsigned)__popcll(__ballot(bin <= (unsigned)b));
    }

    // ---- threshold bin of the 24th smallest (uniform across lanes) ----
    int bstar = 31;
    #pragma unroll
    for (int b = 31; b >= 0; --b) if (cum[b] >= KNN) bstar = b;
    const unsigned limit = (unsigned)(241 + bstar) << 22;

    // ---- pass B: ballot-compacted candidate collection ----
    int nsel = 0;
    for (int base = 0; base < nact; base += 64) {
        int c = base + lane;
        float4 p = pact[c];
        int j = __float_as_int(p.w);
        float dx = p.x - pq.x, dy = p.y - pq.y, dz = p.z - pq.z;
        float d2 = dx * dx + dy * dy + dz * dz;
        unsigned bits = __float_as_uint(d2);
        bool sel = (c < nact) && (j != ia) && (bits < limit);
        unsigned long long m = __ballot(sel);
        int pos = nsel + (int)__popcll(m & lmask);
        if (sel && pos < CAP) s_cand[wv][pos] = make_uint2(bits, (unsigned)j);
        nsel += (int)__popcll(m);
    }
    __builtin_amdgcn_wave_barrier();

    // ---- exact rank select ((d2, j) lex == lax.top_k tie-break) ----
    int n = min(nsel, CAP);
    for (int c = lane; c < n; c += 64) {
        uint2 my = s_cand[wv][c];
        int rank = 0;
        for (int c2 = 0; c2 < n; ++c2) {
            uint2 o = s_cand[wv][c2];
            rank += (o.x < my.x) || (o.x == my.x && o.y < my.y);
        }
        if (rank < KNN) idx[ia * KNN + rank] = (int)my.y;
    }
}

// ---------------- per-atom attention, rank-reduced (1 wave / active atom) -------
__global__ __launch_bounds__(64, 2) void k_attn(
    const float* __restrict__ xyz, const int* __restrict__ seq,
    const int* __restrict__ num_bonds, const float* __restrict__ state,
    const float* __restrict__ grads,
    const float* __restrict__ We, const float* __restrict__ be,
    const float* __restrict__ Wq, const float* __restrict__ Wk,
    const float* __restrict__ Wv0, const float* __restrict__ Wv1,
    const float* __restrict__ Wo0, const float* __restrict__ Wself,
    const float* __restrict__ b0,
    const float4* __restrict__ pact, const int* __restrict__ cnt,
    const int* __restrict__ idxbuf,
    float* __restrict__ out_xyz, float* __restrict__ out_state) {
    const int nact = *cnt;
    if ((int)blockIdx.x >= nact) return;
    const int i = __float_as_int(pact[blockIdx.x].w);
    const int lane = threadIdx.x;
    const int l15 = lane & 15;
    const int h = lane >> 4;

    __shared__ float s_kin[KNN][100];   // [node0(64) | e(32) | inv(3) | pad]
    __shared__ float s_qw[4][100];      // Wk folded with q, per head
    __shared__ float s_wkin[4][100];    // attn-weighted kin, per head
    __shared__ float s_dir[KNN][4];
    __shared__ float s_rbf[KNN][RBF_];
    __shared__ float s_l1j[KNN][3][3];
    __shared__ float s_qin[68];
    __shared__ float s_q[64];
    __shared__ float s_logit[4][KNN];
    __shared__ float s_attn[4][KNN];
    __shared__ float s_o0[64];
    __shared__ float s_v1[KNN][16];
    __shared__ float s_coef[KNN][4];
    __shared__ int   s_j[KNN];
    __shared__ int   s_ok[KNN];
    __shared__ int   s_bc[KNN];
    __shared__ float s_xi[3];

    // ---- stage per-atom inputs ----
    s_qin[lane] = state[i * D0_ + lane];
    if (lane < 3) {
        float g0 = grads[(lane * MTOT + i) * 3 + 0];
        float g1 = grads[(lane * MTOT + i) * 3 + 1];
        float g2 = grads[(lane * MTOT + i) * 3 + 2];
        s_qin[D0_ + lane] = sqrtf(g0 * g0 + g1 * g1 + g2 * g2 + EPS_);
        s_xi[lane] = xyz[i * 3 + lane];
    }
    if (lane < KNN) {
        int j = idxbuf[i * KNN + lane];
        int ok = (j >= 0 && j < MTOT);
        int jj = ok ? j : 0;
        s_j[lane] = jj;
        s_ok[lane] = ok;
        float dx = xyz[jj * 3 + 0] - xyz[i * 3 + 0];
        float dy = xyz[jj * 3 + 1] - xyz[i * 3 + 1];
        float dz = xyz[jj * 3 + 2] - xyz[i * 3 + 2];
        float dist = sqrtf(dx * dx + dy * dy + dz * dz + EPS_);
        s_dir[lane][0] = dx / dist;
        s_dir[lane][1] = dy / dist;
        s_dir[lane][2] = dz / dist;
        s_dir[lane][3] = dist;
        int ri = i / A_, ai = i - ri * A_;
        int rj = jj / A_, aj = jj - rj * A_;
        int b = 0;
        if (rj == ri) b = num_bonds[(seq[ri] * A_ + ai) * A_ + aj];
        s_bc[lane] = min(max(b, 0), 4);
    }
    __syncthreads();

    // ---- q projection ----
    {
        float q = 0.0f;
        for (int c = 0; c < QIN_; ++c) q += s_qin[c] * Wq[c * 64 + lane];
        s_q[lane] = q;
    }
    // ---- rbf ----
    for (int f = lane; f < KNN * RBF_; f += 64) {
        int k = f >> 4, r = f & 15;
        float mu = (6.0f / 15.0f) * (float)r;
        float d = s_dir[k][3] - mu;
        s_rbf[k][r] = expf(-d * d * 2.0f);
    }
    // ---- neighbor node0 gather ----
    for (int k = 0; k < KNN; ++k) s_kin[k][lane] = state[s_j[k] * D0_ + lane];
    // ---- l1 invariants + stash l1j ----
    for (int f = lane; f < KNN * 3; f += 64) {
        int k = f / 3, c = f - 3 * k;
        int jj = s_j[k];
        float g0 = grads[(c * MTOT + jj) * 3 + 0];
        float g1 = grads[(c * MTOT + jj) * 3 + 1];
        float g2 = grads[(c * MTOT + jj) * 3 + 2];
        s_l1j[k][c][0] = g0; s_l1j[k][c][1] = g1; s_l1j[k][c][2] = g2;
        s_kin[k][96 + c] = g0 * s_dir[k][0] + g1 * s_dir[k][1] + g2 * s_dir[k][2];
    }
    if (lane < KNN) s_kin[lane][99] = 0.0f;
    __syncthreads();

    // ---- edge embedding -> kin[:, 64:96] ----
    for (int f = lane; f < KNN * EDGE_; f += 64) {
        int k = f >> 5, d = f & 31;
        float acc = be[d] + We[(RBF_ + s_bc[k]) * EDGE_ + d];
        #pragma unroll
        for (int r = 0; r < RBF_; ++r) acc += s_rbf[k][r] * We[r * EDGE_ + d];
        s_kin[k][64 + d] = acc;
    }
    // ---- fold q into Wk: qW[h][c] = sum_d q[h,d] * Wk[c, h*16+d] ----
    for (int t = 0; t < 7; ++t) {
        int c = t * 16 + l15;
        if (c < 99) {
            const float* wk = &Wk[c * 64 + h * 16];
            float acc = 0.0f;
            #pragma unroll
            for (int d = 0; d < 16; ++d) acc += s_q[h * 16 + d] * wk[d];
            s_qw[h][c] = acc;
        }
    }
    __syncthreads();

    // ---- logits[h][k] = kin[k] . qW[h] ----
    for (int f = lane; f < 96; f += 64) {
        int k = f >> 2, hh = f & 3;
        const float4* k4 = (const float4*)s_kin[k];
        const float4* q4 = (const float4*)s_qw[hh];
        float acc = 0.0f;
        #pragma unroll
        for (int c4 = 0; c4 < 24; ++c4) {
            float4 a = k4[c4], b = q4[c4];
            acc += a.x * b.x + a.y * b.y + a.z * b.z + a.w * b.w;
        }
        acc += s_kin[k][96] * s_qw[hh][96] + s_kin[k][97] * s_qw[hh][97]
             + s_kin[k][98] * s_qw[hh][98];
        s_logit[hh][k] = s_ok[k] ? acc * 0.25f : -1e9f;
    }
    __syncthreads();

    // ---- softmax ----
    float attn[KNN];
    {
        float mx = -1e30f;
        #pragma unroll
        for (int k = 0; k < KNN; ++k) { attn[k] = s_logit[h][k]; mx = fmaxf(mx, attn[k]); }
        float ss = 0.0f;
        #pragma unroll
        for (int k = 0; k < KNN; ++k) { attn[k] = expf(attn[k] - mx); ss += attn[k]; }
        float rs = 1.0f / ss;
        #pragma unroll
        for (int k = 0; k < KNN; ++k) attn[k] *= rs;
    }
    s_attn[h][l15] = attn[l15];
    if (l15 < 8) s_attn[h][16 + l15] = attn[16 + l15];

    // ---- wkin[h][c] = sum_k attn[k] * kin[k][c] ----
    for (int t = 0; t < 7; ++t) {
        int c = t * 16 + l15;
        if (c < 99) {
            float acc = 0.0f;
            #pragma unroll
            for (int k = 0; k < KNN; ++k) acc += attn[k] * s_kin[k][c];
            s_wkin[h][c] = acc;
        }
    }
    // ---- v1[k][u] = kin[k] . Wv1[:,u] ----
    for (int t = 0; t < 6; ++t) {
        int k = (t * 64 + lane) >> 4;
        const float4* k4 = (const float4*)s_kin[k];
        const float* wv = &Wv1[l15];
        float acc = 0.0f;
        #pragma unroll
        for (int c4 = 0; c4 < 24; ++c4) {
            float4 a = k4[c4];
            acc += a.x * wv[(c4 * 4 + 0) * 16] + a.y * wv[(c4 * 4 + 1) * 16]
                 + a.z * wv[(c4 * 4 + 2) * 16] + a.w * wv[(c4 * 4 + 3) * 16];
        }
        acc += s_kin[k][96] * wv[96 * 16] + s_kin[k][97] * wv[97 * 16]
             + s_kin[k][98] * wv[98 * 16];
        s_v1[k][l15] = acc;
    }
    __syncthreads();

    // ---- o0[lane] = sum_c wkin[h][c] * Wv0[c, lane] ----
    {
        float o0 = 0.0f;
        for (int c = 0; c < 99; ++c) o0 += s_wkin[h][c] * Wv0[c * 64 + lane];
        s_o0[lane] = o0;
    }
    __syncthreads();

    // ---- out0 = o0 @ Wo0 + node0 @ Wself + b0 ----
    {
        float acc = b0[lane];
        for (int t = 0; t < 64; ++t) acc += s_o0[t] * Wo0[t * 64 + lane];
        for (int t = 0; t < 64; ++t) acc += s_qin[t] * Wself[t * 64 + lane];
        out_state[i * D0_ + lane] = acc;
    }
    // ---- coef[k][c] = sum_h attn[h][k] * v1[k][h*4+c] ----
    for (int f = lane; f < KNN * 4; f += 64) {
        int k = f >> 2, c = f & 3;
        float a2 = 0.0f;
        #pragma unroll
        for (int hh = 0; hh < 4; ++hh) a2 += s_attn[hh][k] * s_v1[k][hh * 4 + c];
        s_coef[k][c] = a2;
    }
    __syncthreads();

    // ---- vector message -> xyz shift ----
    if (lane < 3) {
        float o1 = 0.0f;
        #pragma unroll
        for (int k = 0; k < KNN; ++k) {
            float t = s_coef[k][0] * s_dir[k][lane];
            t += s_coef[k][1] * s_l1j[k][0][lane];
            t += s_coef[k][2] * s_l1j[k][1][lane];
            t += s_coef[k][3] * s_l1j[k][2][lane];
            o1 += t;
        }
        out_xyz[i * 3 + lane] = s_xi[lane] + o1 / 100.0f;
    }
}

extern "C" void kernel_launch(void* const* d_in, const int* in_sizes, int n_in,
                              void* d_out, int out_size, void* d_ws, size_t ws_size,
                              hipStream_t stream) {
    const int*   seq    = (const int*)d_in[0];
    const float* xyz    = (const float*)d_in[1];
    const int*   aamask = (const int*)d_in[2];
    const int*   nbonds = (const int*)d_in[3];
    const float* state  = (const float*)d_in[4];
    const float* grads  = (const float*)d_in[5];
    const float* We    = (const float*)d_in[7];
    const float* be    = (const float*)d_in[8];
    const float* Wq    = (const float*)d_in[9];
    const float* Wk    = (const float*)d_in[10];
    const float* Wv0   = (const float*)d_in[11];
    const float* Wv1   = (const float*)d_in[12];
    const float* Wo0   = (const float*)d_in[13];
    const float* Wself = (const float*)d_in[14];
    const float* b0    = (const float*)d_in[15];

    float* out_xyz   = (float*)d_out;
    float* out_state = out_xyz + MTOT * 3;

    char* ws = (char*)d_ws;
    int*    cnt  = (int*)ws;                             // 16 B
    float4* pact = (float4*)(ws + 16);                   // (MTOT+64)*16 = 148480 B
    int*    idx  = (int*)(ws + 16 + 148480);             // 884736 B

    k_zero<<<1, 64, 0, stream>>>(cnt);
    k_prep<<<(MTOT + 255) / 256, 256, 0, stream>>>(seq, xyz, aamask, pact,
                                                   out_xyz, cnt);
    k_copy<<<(MTOT * D0_ / 4 + 255) / 256, 256, 0, stream>>>(
        (const float4*)state, (float4*)out_state, MTOT * D0_ / 4);
    k_nbr<<<(MTOT + WPB - 1) / WPB, 256, 0, stream>>>(pact, cnt, idx);
    k_attn<<<MTOT, 64, 0, stream>>>(xyz, seq, nbonds, state, grads, We, be, Wq, Wk,
                                    Wv0, Wv1, Wo0, Wself, b0, pact, cnt, idx,
                                    out_xyz, out_state);
}